// Round 9
// baseline (88.147 us; speedup 1.0000x reference)
//
#include <hip/hip_runtime.h>
#include <hip/hip_bf16.h>

typedef __attribute__((ext_vector_type(8))) short short8;
typedef __attribute__((ext_vector_type(4))) float floatx4;
typedef __attribute__((ext_vector_type(2))) float floatx2;

#define L2EPS 1e-12f

__device__ __forceinline__ unsigned short f2bf(float f) {
  union { float f; unsigned u; } c; c.f = f;
  unsigned u = c.u;
  unsigned r = (u + 0x7fffu + ((u >> 16) & 1u)) >> 16;  // RNE
  return (unsigned short)r;
}

__device__ __forceinline__ void gload_lds16(const void* g, void* l) {
  __builtin_amdgcn_global_load_lds(
      (const __attribute__((address_space(1))) unsigned int*)g,
      (__attribute__((address_space(3))) unsigned int*)l,
      16, 0, 0);
}

// ---------------------------------------------------------------------------
// Kernel 1: per-row inverse L2 norm of W (D rows of length N). One block/row.
// ---------------------------------------------------------------------------
__global__ __launch_bounds__(256) void wnorm_kernel(const float* __restrict__ W,
                                                    float* __restrict__ rnw, int N) {
  const int d = blockIdx.x;
  const float2* row2 = (const float2*)(W + (size_t)d * N);
  const int n2 = N >> 1;
  float s = 0.f;
  for (int i = threadIdx.x; i < n2; i += 256) {
    const float2 v = row2[i];
    s += v.x * v.x + v.y * v.y;
  }
  if (threadIdx.x == 0 && (N & 1)) {
    const float v = W[(size_t)d * N + (N - 1)];
    s += v * v;
  }
#pragma unroll
  for (int off = 32; off > 0; off >>= 1) s += __shfl_xor(s, off);
  __shared__ float red[4];
  if ((threadIdx.x & 63) == 0) red[threadIdx.x >> 6] = s;
  __syncthreads();
  if (threadIdx.x == 0) {
    const float t = red[0] + red[1] + red[2] + red[3];
    rnw[d] = rsqrtf(fmaxf(t, L2EPS));
  }
}

// ---------------------------------------------------------------------------
// Kernel 2 (fused dispatch): blocks [0,nxb): normalize x rows AND fold rnw.
// Blocks [nxb,...): transpose-cast BT[n][d] = bf16(W[d][n]), zero-padded.
// ---------------------------------------------------------------------------
__global__ __launch_bounds__(256) void prep_kernel(const float* __restrict__ x,
                                                   const float* __restrict__ W,
                                                   const float* __restrict__ rnw,
                                                   unsigned short* __restrict__ xb,
                                                   unsigned short* __restrict__ BT,
                                                   int N, int nxb, int nwx) {
  const int bid = blockIdx.x;
  if (bid < nxb) {
    const int lane = threadIdx.x & 63;
    const int wave = threadIdx.x >> 6;
    const int row  = bid * 4 + wave;
    const float4* xr = (const float4*)(x + (size_t)row * 512);
    const float4 v0 = xr[lane * 2];
    const float4 v1 = xr[lane * 2 + 1];
    float s = v0.x*v0.x + v0.y*v0.y + v0.z*v0.z + v0.w*v0.w
            + v1.x*v1.x + v1.y*v1.y + v1.z*v1.z + v1.w*v1.w;
#pragma unroll
    for (int off = 32; off > 0; off >>= 1) s += __shfl_xor(s, off);
    const float r = rsqrtf(fmaxf(s, L2EPS));
    const float4 w0 = ((const float4*)rnw)[lane * 2];
    const float4 w1 = ((const float4*)rnw)[lane * 2 + 1];
    short8 o;
    o[0] = (short)f2bf(v0.x * r * w0.x); o[1] = (short)f2bf(v0.y * r * w0.y);
    o[2] = (short)f2bf(v0.z * r * w0.z); o[3] = (short)f2bf(v0.w * r * w0.w);
    o[4] = (short)f2bf(v1.x * r * w1.x); o[5] = (short)f2bf(v1.y * r * w1.y);
    o[6] = (short)f2bf(v1.z * r * w1.z); o[7] = (short)f2bf(v1.w * r * w1.w);
    *(short8*)(xb + (size_t)row * 512 + lane * 8) = o;
  } else {
    __shared__ unsigned short tile[32][33];
    const int wb = bid - nxb;
    const int n0 = (wb % nwx) * 32;
    const int d0 = (wb / nwx) * 32;
    const int tx = threadIdx.x & 31;
    const int ty = threadIdx.x >> 5;  // 0..7
#pragma unroll
    for (int i = 0; i < 4; ++i) {
      const int dl = ty + i * 8;
      const int n = n0 + tx;
      float v = 0.f;
      if (n < N) v = W[(size_t)(d0 + dl) * N + n];
      tile[tx][dl] = f2bf(v);
    }
    __syncthreads();
#pragma unroll
    for (int i = 0; i < 4; ++i) {
      const int nl = ty + i * 8;
      BT[(size_t)(n0 + nl) * 512 + d0 + tx] = tile[nl][tx];
    }
  }
}

// ---------------------------------------------------------------------------
// Kernel 3: GEMM, r8 skeleton (128x128, 4 waves, BK=64, single LDS buffer,
// compiler-owned schedule, chunk-XOR swizzle, XCD column chunks) with ONE
// change: LDS-staged coalesced epilogue. acc -> padded f32 LDS tile (stride
// 66: all write/read patterns <=2-way banks) -> float2 row-streaming stores
// (256B contiguous per row segment, full 128B lines -> no partial-line RMW).
// ---------------------------------------------------------------------------
union SMemT {
  struct { unsigned short a[128 * 64]; unsigned short b[128 * 64]; } st;
  float ep[128][66];
};

__global__ __launch_bounds__(256, 4) void gemm_kernel(
    const unsigned short* __restrict__ A,   // (4096,512) bf16 (xn * rnw)
    const unsigned short* __restrict__ BT,  // (6016,512) bf16 (W^T)
    float* __restrict__ C,                  // (4096,N) f32
    int N, int nbx, int nby) {
  __shared__ SMemT smem;

  const int tid = threadIdx.x;
  const int l   = tid & 63;
  const int w   = tid >> 6;   // 0..3
  const int wr  = w >> 1;     // 0..1
  const int wc  = w & 1;      // 0..1

  // XCD swizzle: 1504 = 8 x 188; column-major chunks (B-panel L2 reuse).
  const int grid = nbx * nby;
  const int bid  = blockIdx.x;
  int swz = bid;
  if ((grid & 7) == 0) swz = (bid & 7) * (grid >> 3) + (bid >> 3);
  const int bx = swz / nby;
  const int by = swz % nby;
  const int row0 = by * 128;
  const int col0 = bx * 128;

  floatx4 acc[4][4];
#pragma unroll
  for (int m = 0; m < 4; ++m)
#pragma unroll
    for (int n = 0; n < 4; ++n)
      acc[m][n] = (floatx4){0.f, 0.f, 0.f, 0.f};

  // staging: one instr = 256 thr x 16B = 4KB = 32 rows of 128B; 4 per matrix.
  // LDS dest linear (tid*16B); SOURCE chunk pre-swizzled (rule #21):
  // chunk_g = (tid&7) ^ (row&7), row&7 = (tid>>3)&7 (rows step by 32).
  const int srow = tid >> 3;                               // 0..31
  const int sch  = ((tid & 7) ^ (srow & 7)) * 8;           // elems
  const unsigned short* Ap = A  + (size_t)(row0 + srow) * 512 + sch;
  const unsigned short* Bp = BT + (size_t)(col0 + srow) * 512 + sch;
  const int lo = tid * 8;                                  // LDS elems

  // frag-read geometry: elem = row*64 + ((ks*4+q4)^(row&7))*8 (0 conflicts, r3)
  const int ln15 = l & 15;
  const int q4   = l >> 4;
  const int e7   = ln15 & 7;
  const int cs0  = ((q4) ^ e7) * 8;
  const int cs1  = ((4 + q4) ^ e7) * 8;
  const int aoff = (wr * 64 + ln15) * 64;   // + m*1024
  const int boff = (wc * 64 + ln15) * 64;   // + n*1024

  for (int t = 0; t < 8; ++t) {
#pragma unroll
    for (int i = 0; i < 4; ++i)
      gload_lds16(Ap + (size_t)(i * 32) * 512 + t * 64, &smem.st.a[i * 2048 + lo]);
#pragma unroll
    for (int i = 0; i < 4; ++i)
      gload_lds16(Bp + (size_t)(i * 32) * 512 + t * 64, &smem.st.b[i * 2048 + lo]);
    __syncthreads();
#pragma unroll
    for (int ks = 0; ks < 2; ++ks) {
      const int cs = ks ? cs1 : cs0;
      short8 af[4], bf[4];
#pragma unroll
      for (int m = 0; m < 4; ++m) af[m] = *(const short8*)&smem.st.a[aoff + m * 1024 + cs];
#pragma unroll
      for (int n = 0; n < 4; ++n) bf[n] = *(const short8*)&smem.st.b[boff + n * 1024 + cs];
#pragma unroll
      for (int m = 0; m < 4; ++m)
#pragma unroll
        for (int n = 0; n < 4; ++n)
          acc[m][n] = __builtin_amdgcn_mfma_f32_16x16x32_bf16(af[m], bf[n], acc[m][n], 0, 0, 0);
    }
    __syncthreads();
  }

  // ---- LDS-staged coalesced epilogue ----
  // C/D layout: col = lane&15 (+n*16), row = q4*4 + r (+m*16) within wave tile.
  // Two 64-col chunks; waves with wc==ch own chunk ch.
  const int erow = tid >> 5;          // 0..7
  const int ecol = (tid & 31) * 2;    // 0..62
#pragma unroll
  for (int ch = 0; ch < 2; ++ch) {
    if (ch) __syncthreads();          // prev chunk's LDS reads done
    if (wc == ch) {
#pragma unroll
      for (int m = 0; m < 4; ++m)
#pragma unroll
        for (int n = 0; n < 4; ++n)
#pragma unroll
          for (int r = 0; r < 4; ++r)
            smem.ep[wr * 64 + q4 * 4 + m * 16 + r][n * 16 + ln15] = acc[m][n][r];
    }
    __syncthreads();
    const int ccol = col0 + ch * 64 + ecol;
#pragma unroll
    for (int i = 0; i < 16; ++i) {
      const int rr = i * 8 + erow;
      const floatx2 v = *(const floatx2*)&smem.ep[rr][ecol];
      float* dst = C + (size_t)(row0 + rr) * N + ccol;
      if (ccol + 1 < N) {
        *(floatx2*)dst = v;
      } else if (ccol < N) {
        dst[0] = v[0];
      }
    }
  }
}

// ---------------------------------------------------------------------------
extern "C" void kernel_launch(void* const* d_in, const int* in_sizes, int n_in,
                              void* d_out, int out_size, void* d_ws, size_t ws_size,
                              hipStream_t stream) {
  const float* x = (const float*)d_in[0];
  const float* W = (const float*)d_in[1];
  float* out = (float*)d_out;

  const int D = 512;
  const int B = in_sizes[0] / D;            // 4096
  const int N = in_sizes[1] / D;            // 5994
  const int Npad = ((N + 127) / 128) * 128; // 6016

  char* ws = (char*)d_ws;
  unsigned short* xb  = (unsigned short*)ws;                          // B*D*2
  unsigned short* BTb = (unsigned short*)(ws + (size_t)B * D * 2);    // Npad*D*2
  float* rnw = (float*)(ws + (size_t)B * D * 2 + (size_t)Npad * D * 2);

  const int nby = B / 128;         // 32
  const int nbx = Npad / 128;      // 47
  const int nxb = B / 4;           // 1024 xnorm blocks
  const int nwx = Npad / 32;       // 188 wtrans tiles per d-stripe
  const int nwb = nwx * (D / 32);  // 3008 wtrans blocks

  wnorm_kernel<<<D, 256, 0, stream>>>(W, rnw, N);
  prep_kernel<<<nxb + nwb, 256, 0, stream>>>(x, W, rnw, xb, BTb, N, nxb, nwx);
  gemm_kernel<<<nbx * nby, 256, 0, stream>>>(xb, BTb, out, N, nbx, nby);
}

// Round 10
// 80.753 us; speedup vs baseline: 1.0916x; 1.0916x over previous
//
#include <hip/hip_runtime.h>
#include <hip/hip_bf16.h>

typedef __attribute__((ext_vector_type(8))) short short8;
typedef __attribute__((ext_vector_type(4))) float floatx4;

#define L2EPS 1e-12f

__device__ __forceinline__ unsigned short f2bf(float f) {
  union { float f; unsigned u; } c; c.f = f;
  unsigned u = c.u;
  unsigned r = (u + 0x7fffu + ((u >> 16) & 1u)) >> 16;  // RNE
  return (unsigned short)r;
}

__device__ __forceinline__ void gload_lds16(const void* g, void* l) {
  __builtin_amdgcn_global_load_lds(
      (const __attribute__((address_space(1))) unsigned int*)g,
      (__attribute__((address_space(3))) unsigned int*)l,
      16, 0, 0);
}

// ---------------------------------------------------------------------------
// Kernel 1: per-row inverse L2 norm of W (D rows of length N). One block/row.
// ---------------------------------------------------------------------------
__global__ __launch_bounds__(256) void wnorm_kernel(const float* __restrict__ W,
                                                    float* __restrict__ rnw, int N) {
  const int d = blockIdx.x;
  const float2* row2 = (const float2*)(W + (size_t)d * N);
  const int n2 = N >> 1;
  float s = 0.f;
  for (int i = threadIdx.x; i < n2; i += 256) {
    const float2 v = row2[i];
    s += v.x * v.x + v.y * v.y;
  }
  if (threadIdx.x == 0 && (N & 1)) {
    const float v = W[(size_t)d * N + (N - 1)];
    s += v * v;
  }
#pragma unroll
  for (int off = 32; off > 0; off >>= 1) s += __shfl_xor(s, off);
  __shared__ float red[4];
  if ((threadIdx.x & 63) == 0) red[threadIdx.x >> 6] = s;
  __syncthreads();
  if (threadIdx.x == 0) {
    const float t = red[0] + red[1] + red[2] + red[3];
    rnw[d] = rsqrtf(fmaxf(t, L2EPS));
  }
}

// ---------------------------------------------------------------------------
// Kernel 2 (fused dispatch): blocks [0,nxb): normalize x rows AND fold rnw.
// Blocks [nxb,...): transpose-cast BT[n][d] = bf16(W[d][n]), zero-padded.
// ---------------------------------------------------------------------------
__global__ __launch_bounds__(256) void prep_kernel(const float* __restrict__ x,
                                                   const float* __restrict__ W,
                                                   const float* __restrict__ rnw,
                                                   unsigned short* __restrict__ xb,
                                                   unsigned short* __restrict__ BT,
                                                   int N, int nxb, int nwx) {
  const int bid = blockIdx.x;
  if (bid < nxb) {
    const int lane = threadIdx.x & 63;
    const int wave = threadIdx.x >> 6;
    const int row  = bid * 4 + wave;
    const float4* xr = (const float4*)(x + (size_t)row * 512);
    const float4 v0 = xr[lane * 2];
    const float4 v1 = xr[lane * 2 + 1];
    float s = v0.x*v0.x + v0.y*v0.y + v0.z*v0.z + v0.w*v0.w
            + v1.x*v1.x + v1.y*v1.y + v1.z*v1.z + v1.w*v1.w;
#pragma unroll
    for (int off = 32; off > 0; off >>= 1) s += __shfl_xor(s, off);
    const float r = rsqrtf(fmaxf(s, L2EPS));
    const float4 w0 = ((const float4*)rnw)[lane * 2];
    const float4 w1 = ((const float4*)rnw)[lane * 2 + 1];
    short8 o;
    o[0] = (short)f2bf(v0.x * r * w0.x); o[1] = (short)f2bf(v0.y * r * w0.y);
    o[2] = (short)f2bf(v0.z * r * w0.z); o[3] = (short)f2bf(v0.w * r * w0.w);
    o[4] = (short)f2bf(v1.x * r * w1.x); o[5] = (short)f2bf(v1.y * r * w1.y);
    o[6] = (short)f2bf(v1.z * r * w1.z); o[7] = (short)f2bf(v1.w * r * w1.w);
    *(short8*)(xb + (size_t)row * 512 + lane * 8) = o;
  } else {
    __shared__ unsigned short tile[32][33];
    const int wb = bid - nxb;
    const int n0 = (wb % nwx) * 32;
    const int d0 = (wb / nwx) * 32;
    const int tx = threadIdx.x & 31;
    const int ty = threadIdx.x >> 5;  // 0..7
#pragma unroll
    for (int i = 0; i < 4; ++i) {
      const int dl = ty + i * 8;
      const int n = n0 + tx;
      float v = 0.f;
      if (n < N) v = W[(size_t)(d0 + dl) * N + n];
      tile[tx][dl] = f2bf(v);
    }
    __syncthreads();
#pragma unroll
    for (int i = 0; i < 4; ++i) {
      const int nl = ty + i * 8;
      BT[(size_t)(n0 + nl) * 512 + d0 + tx] = tile[nl][tx];
    }
  }
}

// ---------------------------------------------------------------------------
// Kernel 3: GEMM. 128x128, 4 waves (2x2), BK=64, 8 K-tiles.
// NEW dataflow: A double-buffered in LDS (2x16KB, gload_lds, chunk-XOR
// swizzle both sides); B read DIRECTLY from global (L1/L2-resident panel)
// into registers with one-tile prefetch (compiler-scheduled waitcnts, no
// inline asm). One __syncthreads per K-tile. Direct-scalar epilogue
// (measured near-ideal WRITE 103MB in r3/r8; r9's staged variant reverted).
// ---------------------------------------------------------------------------
__global__ __launch_bounds__(256, 3) void gemm_kernel(
    const unsigned short* __restrict__ A,   // (4096,512) bf16 (xn * rnw)
    const unsigned short* __restrict__ BT,  // (6016,512) bf16 (W^T)
    float* __restrict__ C,                  // (4096,N) f32
    int N, int nbx, int nby) {
  __shared__ unsigned short As[2][128 * 64];

  const int tid = threadIdx.x;
  const int l   = tid & 63;
  const int w   = tid >> 6;   // 0..3
  const int wr  = w >> 1;     // 0..1
  const int wc  = w & 1;      // 0..1

  // XCD swizzle: 1504 = 8 x 188; column-major chunks (B-panel L2 reuse).
  const int grid = nbx * nby;
  const int bid  = blockIdx.x;
  int swz = bid;
  if ((grid & 7) == 0) swz = (bid & 7) * (grid >> 3) + (bid >> 3);
  const int bx = swz / nby;
  const int by = swz % nby;
  const int row0 = by * 128;
  const int col0 = bx * 128;

  floatx4 acc[4][4];
#pragma unroll
  for (int m = 0; m < 4; ++m)
#pragma unroll
    for (int n = 0; n < 4; ++n)
      acc[m][n] = (floatx4){0.f, 0.f, 0.f, 0.f};

  // A staging: 4 instrs x 4KB; LDS dest linear, SOURCE chunk pre-swizzled
  // (rule #21): chunk_g = (tid&7) ^ (srow&7).
  const int srow = tid >> 3;                               // 0..31
  const int sch  = ((tid & 7) ^ (srow & 7)) * 8;           // elems
  const unsigned short* Ap = A + (size_t)(row0 + srow) * 512 + sch;
  const int lo = tid * 8;                                  // LDS elems

  // A frag-read: elem = row*64 + ((ks*4+q4)^(row&7))*8. Consecutive-8-lane
  // groups hit 8 distinct 16B bank-groups (conflict-free by r3/r9 model).
  const int ln15 = l & 15;
  const int q4   = l >> 4;
  const int e7   = ln15 & 7;
  const int cs0  = ((q4) ^ e7) * 8;
  const int cs1  = ((4 + q4) ^ e7) * 8;
  const int aoff = (wr * 64 + ln15) * 64;   // + m*1024

  // B direct-load lane base: row = col0 + wc*64 + n*16 + ln15, 16B at q4*8.
  const unsigned short* Bl = BT + (size_t)(col0 + wc * 64 + ln15) * 512 + q4 * 8;

  short8 bEv[8], bOd[8];  // B frags [n*2+ks], even/odd tile (static idx only)

#define STAGE_A(T_) do { \
    _Pragma("unroll") \
    for (int i = 0; i < 4; ++i) \
      gload_lds16(Ap + (size_t)(i * 32) * 512 + (T_) * 64, &As[(T_) & 1][i * 2048 + lo]); \
  } while (0)

#define LOAD_B(T_, BR_) do { \
    _Pragma("unroll") \
    for (int n = 0; n < 4; ++n) { \
      BR_[n * 2 + 0] = *(const short8*)(Bl + n * 8192 + (T_) * 64); \
      BR_[n * 2 + 1] = *(const short8*)(Bl + n * 8192 + (T_) * 64 + 32); \
    } \
  } while (0)

#define COMPUTE(T_, BR_) do { \
    _Pragma("unroll") \
    for (int ks = 0; ks < 2; ++ks) { \
      const int cs = ks ? cs1 : cs0; \
      short8 af[4]; \
      _Pragma("unroll") \
      for (int m = 0; m < 4; ++m) af[m] = *(const short8*)&As[(T_) & 1][aoff + m * 1024 + cs]; \
      _Pragma("unroll") \
      for (int m = 0; m < 4; ++m) \
        _Pragma("unroll") \
        for (int n = 0; n < 4; ++n) \
          acc[m][n] = __builtin_amdgcn_mfma_f32_16x16x32_bf16(af[m], BR_[n * 2 + ks], acc[m][n], 0, 0, 0); \
    } \
  } while (0)

#define GTILE(T_, BCUR_, BNXT_) do { \
    __syncthreads(); \
    if ((T_) < 7) { STAGE_A((T_) + 1); LOAD_B((T_) + 1, BNXT_); } \
    COMPUTE(T_, BCUR_); \
  } while (0)

  // prologue: tile 0 in flight
  STAGE_A(0);
  LOAD_B(0, bEv);

  GTILE(0, bEv, bOd);
  GTILE(1, bOd, bEv);
  GTILE(2, bEv, bOd);
  GTILE(3, bOd, bEv);
  GTILE(4, bEv, bOd);
  GTILE(5, bOd, bEv);
  GTILE(6, bEv, bOd);
  GTILE(7, bOd, bEv);

#undef STAGE_A
#undef LOAD_B
#undef COMPUTE
#undef GTILE

  // epilogue: C/D layout col=lane&15, row=(lane>>4)*4+r; n-inner (r8-proven)
  const int rb = row0 + wr * 64 + q4 * 4;
  const int cb = col0 + wc * 64 + ln15;
#pragma unroll
  for (int m = 0; m < 4; ++m) {
#pragma unroll
    for (int r = 0; r < 4; ++r) {
      const size_t o = (size_t)(rb + m * 16 + r) * N + cb;
#pragma unroll
      for (int n = 0; n < 4; ++n) {
        if (cb + n * 16 < N) C[o + n * 16] = acc[m][n][r];
      }
    }
  }
}

// ---------------------------------------------------------------------------
extern "C" void kernel_launch(void* const* d_in, const int* in_sizes, int n_in,
                              void* d_out, int out_size, void* d_ws, size_t ws_size,
                              hipStream_t stream) {
  const float* x = (const float*)d_in[0];
  const float* W = (const float*)d_in[1];
  float* out = (float*)d_out;

  const int D = 512;
  const int B = in_sizes[0] / D;            // 4096
  const int N = in_sizes[1] / D;            // 5994
  const int Npad = ((N + 127) / 128) * 128; // 6016

  char* ws = (char*)d_ws;
  unsigned short* xb  = (unsigned short*)ws;                          // B*D*2
  unsigned short* BTb = (unsigned short*)(ws + (size_t)B * D * 2);    // Npad*D*2
  float* rnw = (float*)(ws + (size_t)B * D * 2 + (size_t)Npad * D * 2);

  const int nby = B / 128;         // 32
  const int nbx = Npad / 128;      // 47
  const int nxb = B / 4;           // 1024 xnorm blocks
  const int nwx = Npad / 32;       // 188 wtrans tiles per d-stripe
  const int nwb = nwx * (D / 32);  // 3008 wtrans blocks

  wnorm_kernel<<<D, 256, 0, stream>>>(W, rnw, N);
  prep_kernel<<<nxb + nwb, 256, 0, stream>>>(x, W, rnw, xb, BTb, N, nxb, nwx);
  gemm_kernel<<<nbx * nby, 256, 0, stream>>>(xb, BTb, out, N, nbx, nby);
}